// Round 4
// baseline (841.482 us; speedup 1.0000x reference)
//
#include <hip/hip_runtime.h>
#include <cstdint>

typedef unsigned short u16;
typedef unsigned int   u32;

typedef __bf16 bf16_t;
typedef bf16_t bf16x8 __attribute__((ext_vector_type(8)));
typedef float  f32x16 __attribute__((ext_vector_type(16)));

__device__ __forceinline__ float bf2f(u16 v){ u32 u=((u32)v)<<16; float f; __builtin_memcpy(&f,&u,4); return f; }
__device__ __forceinline__ u16 f2bf(float f){ u32 u; __builtin_memcpy(&u,&f,4); u=(u+0x7FFFu+((u>>16)&1u))>>16; return (u16)u; }

// runtime-dtype element fetch -> bf16 bits. fbf=1: buffer is bf16; fbf=0: fp32.
__device__ __forceinline__ u16 cvt(const void* s, long long i, int fbf){
  return fbf ? ((const u16*)s)[i] : f2bf(((const float*)s)[i]);
}

// bijective chunked XCD swizzle (m204)
__device__ __forceinline__ int xcd_swz(int bo, int nwg){
  const int q = nwg >> 3, r = nwg & 7;
  const int xcd = bo & 7, lin = bo >> 3;
  return (xcd < r ? xcd * (q + 1) : r * (q + 1) + (xcd - r) * q) + lin;
}

// ---------------------------------------------------------------------------
// dtype detector (robust thresholds). flags[0]=bf16 inputs, flags[1]=int64 idx.
// ---------------------------------------------------------------------------
__global__ void detect_k(const u32* __restrict__ xf, const u32* __restrict__ ix,
                         int* __restrict__ flags){
  __shared__ int c0, c1;
  const int t = threadIdx.x;
  if (t == 0) { c0 = 0; c1 = 0; }
  __syncthreads();
  int a = 0, b = 0;
  for (int i = t; i < 1024; i += 256) {
    u32 w = xf[i];
    int e = (int)((w >> 7) & 0xFFu);
    if (e >= 100 && e <= 140) a++;
  }
  for (int i = t; i < 8192; i += 256) {
    u32 lo = ix[2 * i], hi = ix[2 * i + 1];
    if (lo != 0xFFFFFFFFu && hi != 0u && hi != 0xFFFFFFFFu) b++;
  }
  atomicAdd(&c0, a); atomicAdd(&c1, b);
  __syncthreads();
  if (t == 0) { flags[0] = (c0 >= 768) ? 1 : 0; flags[1] = (c1 == 0) ? 1 : 0; }
}

// ---------------------------------------------------------------------------
// idx transpose+clamp, coalesced both sides (LDS-tiled).
// idxT[k*Npad + p] = clamped int32 row (invalid/pad -> nsrc); planes
// k in [nK, nKpad) are all-nsrc.
// ---------------------------------------------------------------------------
__global__ __launch_bounds__(256) void itr_k(
    const void* __restrict__ idx, int nK, int nKpad, int Nout, int nsrc,
    int Npad, int* __restrict__ dst, const int* __restrict__ flags){
  __shared__ int tile[28][257];
  const int f64 = flags[1];
  const int t = threadIdx.x;
  const int p0 = blockIdx.x * 256;
  const int32_t*  __restrict__ i32 = (const int32_t*)idx;
  const long long* __restrict__ i64 = (const long long*)idx;
  int pl = t / nK;
  int k  = t - pl * nK;
  const int dp = 256 / nK, dk = 256 - dp * nK;
  while (pl < 256) {
    const int p = p0 + pl;
    int j = -1;
    if (p < Nout) {
      const size_t ii = (size_t)p * nK + k;
      j = f64 ? (int)i64[ii] : i32[ii];
    }
    tile[k][pl] = (j < 0 || j > nsrc) ? nsrc : j;
    pl += dp; k += dk;
    if (k >= nK) { k -= nK; pl += 1; }
  }
  __syncthreads();
  for (int kk = 0; kk < nKpad; ++kk) {
    const int v = (kk < nK) ? tile[kk][t] : nsrc;
    dst[(size_t)kk * Npad + p0 + t] = v;   // coalesced 4B writes
  }
}

// ---------------------------------------------------------------------------
// Gather-GEMM sparse conv, latency-tolerant version.
//   out[p, coloff+co] = epi( sum_{k,ci} src[idx[p,k], ci] * W[k,ci,co] )
// - idx tile staged in LDS as PRE-SHIFTED BYTE OFFSETS (prologue, 1 barrier):
//   removes the per-stage idx global load (the dependency-chain root) and the
//   per-gather address mul from the hot loop.
// - B (weights) staged in LDS when BCH>0 (conflict-free ds_read_b128);
//   otherwise staged from global in the register pipeline.
// - 3-deep software pipeline with statically-named register banks (no
//   runtime-indexed arrays -> no scratch).
// Bounds audit (r3): A-read max = (nsrc+1)*CIN*2 B == allocation; B max index
// < BTf size for all 4 instantiations; p <= Npad-1 == idxT plane extent.
// C/D: col=lane&31, row=(reg&3)+8*(reg>>2)+4*(lane>>5)  [m74/m101 verified]
// ---------------------------------------------------------------------------
template<int CIN, int NF, int NKP, int BCH>
__global__ __launch_bounds__(256) void gconv(
    const u16* __restrict__ src, int nsrc,           // zero row index = nsrc
    const void* __restrict__ idx, int nK,            // legacy path (idxT==null)
    const int* __restrict__ idxT, int Npad,          // transposed clamped idx
    const u16* __restrict__ BTf, int iters,          // iters = nchunk/2
    const u16* __restrict__ bias,
    const u16* __restrict__ resid,                   // may be null; stride=ostride
    void* __restrict__ out, int ostride, int coloff, int Cout,
    int relu, int Nout,
    const int* __restrict__ flags, int out_ext)
{
  constexpr int SH = (CIN == 64) ? 7 : (CIN == 32) ? 6 : 4;  // row byte shift
  constexpr int NB = (BCH == 0) ? 2 * NF : 1;                // staged B regs
  __shared__ int idxL[NKP][256];
  __shared__ __align__(16) u16 BsL[(BCH > 0) ? BCH * NF * 512 : 8];

  const int tid = threadIdx.x;
  const int w = tid >> 6, l = tid & 63;
  const int lm = l & 31, lh = l >> 5;
  const int kloc = lh * 8;
  const int M0 = xcd_swz(blockIdx.x, gridDim.x) * 256;
  const int fbf = flags[0], f64 = flags[1];
  const int pl0 = 2 * w * 32 + lm;      // in-block point slot, m-frag 0

  // ---- prologue: stage idx tile (byte offsets) + B tile ----
  for (int i = tid; i < NKP * 256; i += 256) {
    const int k = i >> 8, pl = i & 255, p = M0 + pl;
    int r;
    if (idxT) {
      r = idxT[(size_t)k * Npad + p];
    } else {
      int j = -1;
      if (k < nK && p < Nout) {
        const size_t ii = (size_t)p * nK + k;
        j = f64 ? (int)((const long long*)idx)[ii] : ((const int32_t*)idx)[ii];
      }
      r = (j < 0 || j > nsrc) ? nsrc : j;
    }
    idxL[k][pl] = r << SH;
  }
  if constexpr (BCH > 0) {
    for (int i = tid; i < BCH * NF * 512; i += 256) BsL[i] = BTf[i];
  }
  __syncthreads();

  f32x16 acc[2][NF];
  #pragma unroll
  for (int mm = 0; mm < 2; ++mm)
    #pragma unroll
    for (int nf = 0; nf < NF; ++nf)
      #pragma unroll
      for (int e = 0; e < 16; ++e) acc[mm][nf][e] = 0.f;

  // one stage = 2 chunks (one 16-wide K slice each)
  auto LD = [&](int it, uint4 (&A)[4], uint4 (&B)[NB]) {
    const int c0 = 2 * it;
    if constexpr (CIN >= 32) {
      const int k = (CIN == 64) ? (c0 >> 2) : (c0 >> 1);
      const int o0 = idxL[k][pl0];
      const int o1 = idxL[k][pl0 + 32];
      const char* s0 = (const char*)src + o0;
      const char* s1 = (const char*)src + o1;
      #pragma unroll
      for (int s = 0; s < 2; ++s) {
        const int c = c0 + s;
        const int ci2 = ((CIN == 64) ? (((c & 3) << 4) + kloc) : (((c & 1) << 4) + kloc)) * 2;
        A[s * 2 + 0] = *(const uint4*)(s0 + ci2);
        A[s * 2 + 1] = *(const uint4*)(s1 + ci2);
      }
    } else {           // CIN == 8: k differs per chunk and lane-half
      #pragma unroll
      for (int s = 0; s < 2; ++s) {
        const int c = c0 + s;
        const int k = c * 2 + lh;
        const int o0 = idxL[k][pl0];
        const int o1 = idxL[k][pl0 + 32];
        A[s * 2 + 0] = *(const uint4*)((const char*)src + o0);
        A[s * 2 + 1] = *(const uint4*)((const char*)src + o1);
      }
    }
    if constexpr (BCH == 0) {
      #pragma unroll
      for (int s = 0; s < 2; ++s)
        #pragma unroll
        for (int nf = 0; nf < NF; ++nf)
          B[s * NF + nf] = *(const uint4*)(BTf + (((size_t)(c0 + s) * NF + nf) * 64 + l) * 8);
    }
  };

  auto MM = [&](int it, const uint4 (&A)[4], const uint4 (&B)[NB]) {
    const int c0 = 2 * it;
    #pragma unroll
    for (int s = 0; s < 2; ++s) {
      const bf16x8 a0 = __builtin_bit_cast(bf16x8, A[s * 2 + 0]);
      const bf16x8 a1 = __builtin_bit_cast(bf16x8, A[s * 2 + 1]);
      #pragma unroll
      for (int nf = 0; nf < NF; ++nf) {
        bf16x8 b;
        if constexpr (BCH > 0) b = *(const bf16x8*)&BsL[(((c0 + s) * NF + nf) * 64 + l) * 8];
        else                   b = __builtin_bit_cast(bf16x8, B[s * NF + nf]);
        acc[0][nf] = __builtin_amdgcn_mfma_f32_32x32x16_bf16(a0, b, acc[0][nf], 0, 0, 0);
        acc[1][nf] = __builtin_amdgcn_mfma_f32_32x32x16_bf16(a1, b, acc[1][nf], 0, 0, 0);
      }
    }
  };

  // 3-deep pipeline, statically-named banks (rotation verified iters=7/16/27/54)
  uint4 A0[4], A1[4], A2[4], B0[NB], B1[NB], B2[NB];
  LD(0, A0, B0);
  if (iters > 1) LD(1, A1, B1);
  for (int it = 0; it < iters; it += 3) {
    if (it + 2 < iters) LD(it + 2, A2, B2);
    MM(it, A0, B0);
    if (it + 3 < iters) LD(it + 3, A0, B0);
    if (it + 1 < iters) MM(it + 1, A1, B1);
    if (it + 4 < iters) LD(it + 4, A1, B1);
    if (it + 2 < iters) MM(it + 2, A2, B2);
  }

  const int fp32out = out_ext && !fbf;
  #pragma unroll
  for (int mm = 0; mm < 2; ++mm) {
    #pragma unroll
    for (int nf = 0; nf < NF; ++nf) {
      const int co = nf * 32 + lm;
      if (co >= Cout) continue;
      const float bv = bf2f(bias[co]);
      #pragma unroll
      for (int r = 0; r < 16; ++r) {
        const int m = (r & 3) + 8 * (r >> 2) + 4 * lh;
        const int p = M0 + (2 * w + mm) * 32 + m;
        if (p >= Nout) continue;
        float v = acc[mm][nf][r] + bv;
        if (resid) v += bf2f(resid[(size_t)p * ostride + coloff + co]);
        if (relu && v < 0.f) v = 0.f;
        const size_t ofs = (size_t)p * ostride + coloff + co;
        if (fp32out) ((float*)out)[ofs] = v;
        else         ((u16*)out)[ofs] = f2bf(v);
      }
    }
  }
}

// ---------------------------------------------------------------------------
// Weight prep: coalesced per-chunk B fragments.
//   BTf[((chunk*NF+nf)*64 + lane)*8 + e] = W'[kk][co],
//   co = nf*32 + (lane&31), kk = chunk*16 + (lane>>5)*8 + e.
// ---------------------------------------------------------------------------
struct PrepJob {
  const void* src; long long eoff; u16* dst;
  int nK, Cin, Cout, COPAD, KKpad, flat, count;
};
struct PrepArgs { PrepJob j[22]; };

__global__ void prep_k(PrepArgs a, const int* __restrict__ flags){
  PrepJob jb = a.j[blockIdx.y];
  const int fbf = flags[0];
  if (jb.flat) {
    for (int t = blockIdx.x * 256 + threadIdx.x; t < jb.count; t += gridDim.x * 256)
      jb.dst[t] = cvt(jb.src, jb.eoff + t, fbf);
    return;
  }
  const int total = jb.COPAD * jb.KKpad;
  const int NFj = jb.COPAD >> 5;            // 1 or 2
  const int kkmax = jb.nK * jb.Cin;
  for (int t = blockIdx.x * 256 + threadIdx.x; t < total; t += gridDim.x * 256) {
    const int e  = t & 7;
    const int lj = (t >> 3) & 63;
    const int cn = t >> 9;                  // chunk*NF + nf
    const int nf = cn & (NFj - 1);
    const int chunk = cn >> (NFj - 1);
    const int co = nf * 32 + (lj & 31);
    const int kk = chunk * 16 + ((lj >> 5) << 3) + e;
    u16 v = 0;
    if (co < jb.Cout && kk < kkmax)
      v = cvt(jb.src, jb.eoff + (long long)kk * jb.Cout + co, fbf);
    jb.dst[t] = v;
  }
}

// xsum = x_feat + f1_ref -> bf16, plus zero row at index N. 8 elems/thread.
__global__ void xsum_k(const void* __restrict__ xa, const void* __restrict__ xb,
                       u16* __restrict__ dst, int n8valid, int n8tot,
                       const int* __restrict__ flags){
  int t = blockIdx.x * 256 + threadIdx.x;
  if (t >= n8tot) return;
  const int fbf = flags[0];
  union { uint4 v; u16 h[8]; } O;
  if (t < n8valid) {
    if (fbf) {
      union { uint4 v; u16 h[8]; } A, B;
      A.v = ((const uint4*)xa)[t];
      B.v = ((const uint4*)xb)[t];
      #pragma unroll
      for (int e = 0; e < 8; ++e) O.h[e] = f2bf(bf2f(A.h[e]) + bf2f(B.h[e]));
    } else {
      const float4* fa = (const float4*)xa;
      const float4* fb = (const float4*)xb;
      float4 a0 = fa[2 * t], a1 = fa[2 * t + 1];
      float4 b0 = fb[2 * t], b1 = fb[2 * t + 1];
      O.h[0] = f2bf(a0.x + b0.x); O.h[1] = f2bf(a0.y + b0.y);
      O.h[2] = f2bf(a0.z + b0.z); O.h[3] = f2bf(a0.w + b0.w);
      O.h[4] = f2bf(a1.x + b1.x); O.h[5] = f2bf(a1.y + b1.y);
      O.h[6] = f2bf(a1.z + b1.z); O.h[7] = f2bf(a1.w + b1.w);
    }
  } else {
    O.v = make_uint4(0, 0, 0, 0);
  }
  ((uint4*)dst)[t] = O.v;
}

// zero the gather "no neighbor" rows (ws re-poisoned every call)
__global__ void zrows_k(u16* out1, int N, u16* od0, u16* od1, u16* h8, u16* t8, int N2){
  int t = threadIdx.x;
  if (t < 64) out1[(size_t)N * 64 + t] = 0;
  if (t < 32) od0[(size_t)N2 * 32 + t] = 0;
  if (t < 32) od1[(size_t)N2 * 32 + t] = 0;
  if (t < 8)  h8[(size_t)N2 * 8 + t] = 0;
  if (t < 8)  t8[(size_t)N2 * 8 + t] = 0;
}

// t8 = relu(od @ W(32x8) + b)   one point/thread. W,b bf16 from ws.
__global__ void t8lin_k(const u16* __restrict__ od, const u16* __restrict__ wsrc,
                        const u16* __restrict__ bsrc, u16* __restrict__ t8, int N2){
  __shared__ u16 wl[256];
  int t = threadIdx.x;
  wl[t] = wsrc[t];
  __syncthreads();
  int p = blockIdx.x * 256 + t;
  if (p >= N2) return;
  union { uint4 v[4]; u16 h[32]; } R;
  const uint4* rp = (const uint4*)(od + (size_t)p * 32);
  R.v[0] = rp[0]; R.v[1] = rp[1]; R.v[2] = rp[2]; R.v[3] = rp[3];
  float acc[8];
  #pragma unroll
  for (int o = 0; o < 8; ++o) acc[o] = bf2f(bsrc[o]);
  #pragma unroll
  for (int c = 0; c < 32; ++c) {
    float f = bf2f(R.h[c]);
    #pragma unroll
    for (int o = 0; o < 8; ++o) acc[o] += f * bf2f(wl[c * 8 + o]);
  }
  union { uint4 v; u16 h[8]; } O;
  #pragma unroll
  for (int o = 0; o < 8; ++o) { float v = acc[o]; if (v < 0.f) v = 0.f; O.h[o] = f2bf(v); }
  ((uint4*)(t8 + (size_t)p * 8))[0] = O.v;
}

// odout[:,16:32] = t2 @ W(8x16) + b + odin[:,16:32]. W,b bf16 from ws.
__global__ void o1lin_k(const u16* __restrict__ t2, const u16* __restrict__ wsrc,
                        const u16* __restrict__ bsrc, const u16* __restrict__ odin,
                        u16* __restrict__ odout, int N2){
  __shared__ u16 wl[128];
  int t = threadIdx.x;
  if (t < 128) wl[t] = wsrc[t];
  __syncthreads();
  int p = blockIdx.x * 256 + t;
  if (p >= N2) return;
  union { uint4 v; u16 h[8]; } R; R.v = ((const uint4*)(t2 + (size_t)p * 8))[0];
  union { uint4 v[2]; u16 h[16]; } Rs;
  const uint4* rp = (const uint4*)(odin + (size_t)p * 32 + 16);
  Rs.v[0] = rp[0]; Rs.v[1] = rp[1];
  float acc[16];
  #pragma unroll
  for (int o = 0; o < 16; ++o) acc[o] = bf2f(bsrc[o]) + bf2f(Rs.h[o]);
  #pragma unroll
  for (int c = 0; c < 8; ++c) {
    float f = bf2f(R.h[c]);
    #pragma unroll
    for (int o = 0; o < 16; ++o) acc[o] += f * bf2f(wl[c * 16 + o]);
  }
  union { uint4 v[2]; u16 h[16]; } O;
  #pragma unroll
  for (int o = 0; o < 16; ++o) O.h[o] = f2bf(acc[o]);
  uint4* op = (uint4*)(odout + (size_t)p * 32 + 16);
  op[0] = O.v[0]; op[1] = O.v[1];
}

extern "C" void kernel_launch(void* const* d_in, const int* in_sizes, int n_in,
                              void* d_out, int out_size, void* d_ws, size_t ws_size,
                              hipStream_t stream) {
  const void* x_feat = d_in[0];
  const void* f1_ref = d_in[1];
  const void* w1   = d_in[2];
  const void* b1   = d_in[3];
  const void* wd   = d_in[4];
  const void* bd   = d_in[5];
  const void* rw00 = d_in[6];
  const void* rb00 = d_in[7];
  const void* rw01 = d_in[8];
  const void* rb01 = d_in[9];
  const void* rw10 = d_in[10];
  const void* rb10 = d_in[11];
  const void* rw11 = d_in[12];
  const void* rb11 = d_in[13];
  const void* rw12 = d_in[14];
  const void* rb12 = d_in[15];
  const void* w4   = d_in[16];
  const void* b4   = d_in[17];
  const void* idx1 = d_in[18];
  const void* idxd = d_in[19];
  const void* idx2 = d_in[20];

  const int N  = in_sizes[0] / 64;
  const int N2 = out_size / 8;

  const int nb1 = (N + 255) / 256;
  const int nb2 = (N2 + 255) / 256;
  const int Npad1 = nb1 * 256;
  const int Npad2 = nb2 * 256;

  // ---- workspace carve (256B aligned) ----
  size_t off = 0;
  auto carve = [&](size_t n) { void* p = (char*)d_ws + off; off = (off + n + 255) & ~(size_t)255; return p; };
  int* flags = (int*)carve(64 * sizeof(int));
  u16* xsum = (u16*)carve((size_t)(N + 1) * 64 * 2);
  u16* out1 = (u16*)carve((size_t)(N + 1) * 64 * 2);
  u16* od0  = (u16*)carve((size_t)(N2 + 1) * 32 * 2);
  u16* od1  = (u16*)carve((size_t)(N2 + 1) * 32 * 2);
  u16* h8   = (u16*)carve((size_t)(N2 + 1) * 8 * 2);
  u16* t8   = (u16*)carve((size_t)(N2 + 1) * 8 * 2);
  u16* t2   = (u16*)carve((size_t)(N2 + 1) * 8 * 2);
  u16* smallw = (u16*)carve((size_t)2048 * 2);
  u16* BT1  = (u16*)carve((size_t)64 * 1728 * 2);
  u16* BTd  = (u16*)carve((size_t)32 * 512 * 2);
  u16* BT00 = (u16*)carve((size_t)3 * 32 * 864 * 2);
  u16* BT01 = (u16*)carve((size_t)3 * 32 * 224 * 2);
  u16* BT11 = (u16*)carve((size_t)3 * 32 * 224 * 2);
  u16* BT4  = (u16*)carve((size_t)32 * 864 * 2);
  const size_t base_off = off;
  // transposed idx maps (optional — legacy path if ws too small)
  int* idx1T = (int*)carve((size_t)27 * Npad1 * 4);
  int* idxdT = (int*)carve((size_t)8  * Npad2 * 4);
  int* idx2T = (int*)carve((size_t)28 * Npad2 * 4);   // k=27 pad plane for CIN=8
  const int useT = (off <= ws_size);
  if (base_off > ws_size) return;
  if (!useT) { idx1T = nullptr; idxdT = nullptr; idx2T = nullptr; }

  // smallw layout (bf16 elements)
  u16* cb1   = smallw + 0;     // 64
  u16* cbd   = smallw + 64;    // 32
  u16* crb00 = smallw + 96;    // 24
  u16* crb01 = smallw + 120;   // 48
  u16* crb10 = smallw + 168;   // 24
  u16* crb11 = smallw + 192;   // 24
  u16* crb12 = smallw + 216;   // 48
  u16* cb4   = smallw + 264;   // 8
  u16* crw10 = smallw + 272;   // 768
  u16* crw12 = smallw + 1040;  // 384

  detect_k<<<1, 256, 0, stream>>>((const u32*)x_feat, (const u32*)idx1, flags);

  // ---- weight prep (coalesced fragment layout) ----
  PrepArgs pa;
  pa.j[0]  = { w1, 0, BT1, 27, 64, 64, 64, 1728, 0, 0 };
  pa.j[1]  = { wd, 0, BTd,  8, 64, 32, 32,  512, 0, 0 };
  for (int i = 0; i < 3; ++i) {
    pa.j[2 + i] = { rw00, (long long)i * 6912, BT00 + (size_t)i * 32 * 864, 27, 32,  8, 32, 864, 0, 0 };
    pa.j[5 + i] = { rw01, (long long)i * 3456, BT01 + (size_t)i * 32 * 224, 27,  8, 16, 32, 224, 0, 0 };
    pa.j[8 + i] = { rw11, (long long)i * 1728, BT11 + (size_t)i * 32 * 224, 27,  8,  8, 32, 224, 0, 0 };
  }
  pa.j[11] = { w4, 0, BT4, 27, 32, 8, 32, 864, 0, 0 };
  pa.j[12] = { b1,   0, cb1,   0,0,0,0,0, 1, 64 };
  pa.j[13] = { bd,   0, cbd,   0,0,0,0,0, 1, 32 };
  pa.j[14] = { rb00, 0, crb00, 0,0,0,0,0, 1, 24 };
  pa.j[15] = { rb01, 0, crb01, 0,0,0,0,0, 1, 48 };
  pa.j[16] = { rb10, 0, crb10, 0,0,0,0,0, 1, 24 };
  pa.j[17] = { rb11, 0, crb11, 0,0,0,0,0, 1, 24 };
  pa.j[18] = { rb12, 0, crb12, 0,0,0,0,0, 1, 48 };
  pa.j[19] = { b4,   0, cb4,   0,0,0,0,0, 1, 8 };
  pa.j[20] = { rw10, 0, crw10, 0,0,0,0,0, 1, 768 };
  pa.j[21] = { rw12, 0, crw12, 0,0,0,0,0, 1, 384 };
  prep_k<<<dim3(432, 22), 256, 0, stream>>>(pa, flags);

  if (useT) {
    itr_k<<<nb1, 256, 0, stream>>>(idx1, 27, 27, N,  N,  Npad1, idx1T, flags);
    itr_k<<<nb2, 256, 0, stream>>>(idxd,  8,  8, N2, N,  Npad2, idxdT, flags);
    itr_k<<<nb2, 256, 0, stream>>>(idx2, 27, 28, N2, N2, Npad2, idx2T, flags);
  }

  const int n8valid = N * 8, n8tot = (N + 1) * 8;
  xsum_k<<<(n8tot + 255) / 256, 256, 0, stream>>>(x_feat, f1_ref, xsum, n8valid, n8tot, flags);
  zrows_k<<<1, 256, 0, stream>>>(out1, N, od0, od1, h8, t8, N2);

  // conv1: 27x64->64, relu  (idx-LDS 27KB, B global)
  gconv<64, 2, 27, 0><<<nb1, 256, 0, stream>>>(xsum, N, idx1, 27, idx1T, Npad1, BT1, 54,
                                               cb1, nullptr, out1, 64, 0, 64, 1, N, flags, 0);
  // down: 8x64->32, relu   (idx-LDS 8KB, B-LDS 32KB)
  gconv<64, 1, 8, 32><<<nb2, 256, 0, stream>>>(out1, N, idxd, 8, idxdT, Npad2, BTd, 16,
                                               cbd, nullptr, od0, 32, 0, 32, 1, N2, flags, 0);
  // residual blocks
  for (int i = 0; i < 3; ++i) {
    u16* oin  = (i & 1) ? od1 : od0;
    u16* oout = (i & 1) ? od0 : od1;
    gconv<32, 1, 27, 0><<<nb2, 256, 0, stream>>>(oin, N2, idx2, 27, idx2T, Npad2, BT00 + (size_t)i * 32 * 864, 27,
                                                 crb00 + i * 8, nullptr, h8, 8, 0, 8, 1, N2, flags, 0);
    t8lin_k<<<nb2, 256, 0, stream>>>(oin, crw10 + i * 256, crb10 + i * 8, t8, N2);
    gconv<8, 1, 28, 14><<<nb2, 256, 0, stream>>>(h8, N2, idx2, 27, idx2T, Npad2, BT01 + (size_t)i * 32 * 224, 7,
                                                 crb01 + i * 16, oin, oout, 32, 0, 16, 0, N2, flags, 0);
    gconv<8, 1, 28, 14><<<nb2, 256, 0, stream>>>(t8, N2, idx2, 27, idx2T, Npad2, BT11 + (size_t)i * 32 * 224, 7,
                                                 crb11 + i * 8, nullptr, t2, 8, 0, 8, 1, N2, flags, 0);
    o1lin_k<<<nb2, 256, 0, stream>>>(t2, crw12 + i * 128, crb12 + i * 16, oin, oout, N2);
  }
  // enc4: 27x32->8, no relu -> d_out (dtype per flags[0])
  gconv<32, 1, 27, 0><<<nb2, 256, 0, stream>>>(od1, N2, idx2, 27, idx2T, Npad2, BT4, 27,
                                               cb4, nullptr, d_out, 8, 0, 8, 0, N2, flags, 1);
}

// Round 5
// 698.495 us; speedup vs baseline: 1.2047x; 1.2047x over previous
//
#include <hip/hip_runtime.h>
#include <cstdint>

typedef unsigned short u16;
typedef unsigned int   u32;

typedef __bf16 bf16_t;
typedef bf16_t bf16x8 __attribute__((ext_vector_type(8)));
typedef float  f32x16 __attribute__((ext_vector_type(16)));

__device__ __forceinline__ float bf2f(u16 v){ u32 u=((u32)v)<<16; float f; __builtin_memcpy(&f,&u,4); return f; }
__device__ __forceinline__ u16 f2bf(float f){ u32 u; __builtin_memcpy(&u,&f,4); u=(u+0x7FFFu+((u>>16)&1u))>>16; return (u16)u; }

// runtime-dtype element fetch -> bf16 bits. fbf=1: buffer is bf16; fbf=0: fp32.
__device__ __forceinline__ u16 cvt(const void* s, long long i, int fbf){
  return fbf ? ((const u16*)s)[i] : f2bf(((const float*)s)[i]);
}

// bijective chunked XCD swizzle (m204)
__device__ __forceinline__ int xcd_swz(int bo, int nwg){
  const int q = nwg >> 3, r = nwg & 7;
  const int xcd = bo & 7, lin = bo >> 3;
  return (xcd < r ? xcd * (q + 1) : r * (q + 1) + (xcd - r) * q) + lin;
}

// ---------------------------------------------------------------------------
// dtype detector (robust thresholds). flags[0]=bf16 inputs, flags[1]=int64 idx.
// ---------------------------------------------------------------------------
__global__ void detect_k(const u32* __restrict__ xf, const u32* __restrict__ ix,
                         int* __restrict__ flags){
  __shared__ int c0, c1;
  const int t = threadIdx.x;
  if (t == 0) { c0 = 0; c1 = 0; }
  __syncthreads();
  int a = 0, b = 0;
  for (int i = t; i < 1024; i += 256) {
    u32 w = xf[i];
    int e = (int)((w >> 7) & 0xFFu);
    if (e >= 100 && e <= 140) a++;
  }
  for (int i = t; i < 8192; i += 256) {
    u32 lo = ix[2 * i], hi = ix[2 * i + 1];
    if (lo != 0xFFFFFFFFu && hi != 0u && hi != 0xFFFFFFFFu) b++;
  }
  atomicAdd(&c0, a); atomicAdd(&c1, b);
  __syncthreads();
  if (t == 0) { flags[0] = (c0 >= 768) ? 1 : 0; flags[1] = (c1 == 0) ? 1 : 0; }
}

// ---------------------------------------------------------------------------
// idx transpose+clamp, coalesced both sides (LDS-tiled).
// idxT[k*Npad + p] = clamped int32 row (invalid/pad -> nsrc); planes
// k in [nK, nKpad) are all-nsrc.
// ---------------------------------------------------------------------------
__global__ __launch_bounds__(256) void itr_k(
    const void* __restrict__ idx, int nK, int nKpad, int Nout, int nsrc,
    int Npad, int* __restrict__ dst, const int* __restrict__ flags){
  __shared__ int tile[28][257];
  const int f64 = flags[1];
  const int t = threadIdx.x;
  const int p0 = blockIdx.x * 256;
  const int32_t*  __restrict__ i32 = (const int32_t*)idx;
  const long long* __restrict__ i64 = (const long long*)idx;
  int pl = t / nK;
  int k  = t - pl * nK;
  const int dp = 256 / nK, dk = 256 - dp * nK;
  while (pl < 256) {
    const int p = p0 + pl;
    int j = -1;
    if (p < Nout) {
      const size_t ii = (size_t)p * nK + k;
      j = f64 ? (int)i64[ii] : i32[ii];
    }
    tile[k][pl] = (j < 0 || j > nsrc) ? nsrc : j;
    pl += dp; k += dk;
    if (k >= nK) { k -= nK; pl += 1; }
  }
  __syncthreads();
  for (int kk = 0; kk < nKpad; ++kk) {
    const int v = (kk < nK) ? tile[kk][t] : nsrc;
    dst[(size_t)kk * Npad + p0 + t] = v;   // coalesced 4B writes
  }
}

// ---------------------------------------------------------------------------
// Gather-GEMM sparse conv, latency-tolerant.
//   out[p, coloff+co] = epi( sum_{k,ci} src[idx[p,k], ci] * W[k,ci,co] )
// - idx tile in LDS as PRE-SHIFTED BYTE OFFSETS (uint4-vectorized prologue).
// - B in LDS when BCH>0 (uint4-vectorized staging); else global (L2-hit).
// - 3-deep software pipeline, statically-named register banks.
// - split epilogue: cols >= o2off go to out2 (relu), else out (+resid, relu?);
//   bias2/b2off selects a second bias vector for high columns.
// C/D: col=lane&31, row=(reg&3)+8*(reg>>2)+4*(lane>>5)  [m74/m101 verified]
// ---------------------------------------------------------------------------
template<int CIN, int NF, int NKP, int BCH>
__global__ __launch_bounds__(256) void gconv(
    const u16* __restrict__ src, int nsrc,           // zero row index = nsrc
    const void* __restrict__ idx, int nK,            // legacy path (idxT==null)
    const int* __restrict__ idxT, int Npad,          // transposed clamped idx
    const u16* __restrict__ BTf, int iters,          // iters = nchunk/2
    const u16* __restrict__ bias,
    const u16* __restrict__ bias2, int b2off,        // bias for co>=b2off (opt)
    const u16* __restrict__ resid,                   // may be null; stride=ostride
    void* __restrict__ out, int ostride, int coloff, int Cout,
    int relu,
    u16* __restrict__ out2, int o2st, int o2off,     // split output (opt, relu)
    int Nout, const int* __restrict__ flags, int out_ext)
{
  constexpr int SH = (CIN == 64) ? 7 : (CIN == 32) ? 6 : (CIN == 16) ? 5 : 4;
  constexpr int NB = (BCH == 0) ? 2 * NF : 1;                // staged B regs
  __shared__ int idxL[NKP][256];
  __shared__ __align__(16) u16 BsL[(BCH > 0) ? BCH * NF * 512 : 8];

  const int tid = threadIdx.x;
  const int w = tid >> 6, l = tid & 63;
  const int lm = l & 31, lh = l >> 5;
  const int kloc = lh * 8;
  const int M0 = xcd_swz(blockIdx.x, gridDim.x) * 256;
  const int fbf = flags[0], f64 = flags[1];
  const int pl0 = 2 * w * 32 + lm;      // in-block point slot, m-frag 0

  // ---- prologue: stage idx tile (byte offsets) + B tile, vectorized ----
  if (idxT) {
    for (int i = tid; i < NKP * 64; i += 256) {
      const int k = i >> 6, g = (i & 63) << 2;
      const uint4 v = *(const uint4*)(idxT + (size_t)k * Npad + M0 + g);
      *(int4*)&idxL[k][g] = make_int4((int)v.x << SH, (int)v.y << SH,
                                      (int)v.z << SH, (int)v.w << SH);
    }
  } else {
    for (int i = tid; i < NKP * 256; i += 256) {
      const int k = i >> 8, pl = i & 255, p = M0 + pl;
      int j = -1;
      if (k < nK && p < Nout) {
        const size_t ii = (size_t)p * nK + k;
        j = f64 ? (int)((const long long*)idx)[ii] : ((const int32_t*)idx)[ii];
      }
      const int r = (j < 0 || j > nsrc) ? nsrc : j;
      idxL[k][pl] = r << SH;
    }
  }
  if constexpr (BCH > 0) {
    for (int i = tid; i < BCH * NF * 64; i += 256)
      ((uint4*)BsL)[i] = ((const uint4*)BTf)[i];
  }
  __syncthreads();

  f32x16 acc[2][NF];
  #pragma unroll
  for (int mm = 0; mm < 2; ++mm)
    #pragma unroll
    for (int nf = 0; nf < NF; ++nf)
      #pragma unroll
      for (int e = 0; e < 16; ++e) acc[mm][nf][e] = 0.f;

  // one stage = 2 chunks (one 16-wide K slice each)
  auto LD = [&](int it, uint4 (&A)[4], uint4 (&B)[NB]) {
    const int c0 = 2 * it;
    if constexpr (CIN >= 32) {
      const int k = (CIN == 64) ? (c0 >> 2) : (c0 >> 1);
      const int o0 = idxL[k][pl0];
      const int o1 = idxL[k][pl0 + 32];
      const char* s0 = (const char*)src + o0;
      const char* s1 = (const char*)src + o1;
      #pragma unroll
      for (int s = 0; s < 2; ++s) {
        const int c = c0 + s;
        const int ci2 = ((CIN == 64) ? (((c & 3) << 4) + kloc) : (((c & 1) << 4) + kloc)) * 2;
        A[s * 2 + 0] = *(const uint4*)(s0 + ci2);
        A[s * 2 + 1] = *(const uint4*)(s1 + ci2);
      }
    } else if constexpr (CIN == 16) {   // one tap per chunk, 32B rows
      #pragma unroll
      for (int s = 0; s < 2; ++s) {
        const int k = c0 + s;
        const int o0 = idxL[k][pl0];
        const int o1 = idxL[k][pl0 + 32];
        A[s * 2 + 0] = *(const uint4*)((const char*)src + o0 + lh * 16);
        A[s * 2 + 1] = *(const uint4*)((const char*)src + o1 + lh * 16);
      }
    } else {           // CIN == 8: k differs per chunk and lane-half
      #pragma unroll
      for (int s = 0; s < 2; ++s) {
        const int c = c0 + s;
        const int k = c * 2 + lh;
        const int o0 = idxL[k][pl0];
        const int o1 = idxL[k][pl0 + 32];
        A[s * 2 + 0] = *(const uint4*)((const char*)src + o0);
        A[s * 2 + 1] = *(const uint4*)((const char*)src + o1);
      }
    }
    if constexpr (BCH == 0) {
      #pragma unroll
      for (int s = 0; s < 2; ++s)
        #pragma unroll
        for (int nf = 0; nf < NF; ++nf)
          B[s * NF + nf] = *(const uint4*)(BTf + (((size_t)(c0 + s) * NF + nf) * 64 + l) * 8);
    }
  };

  auto MM = [&](int it, const uint4 (&A)[4], const uint4 (&B)[NB]) {
    const int c0 = 2 * it;
    #pragma unroll
    for (int s = 0; s < 2; ++s) {
      const bf16x8 a0 = __builtin_bit_cast(bf16x8, A[s * 2 + 0]);
      const bf16x8 a1 = __builtin_bit_cast(bf16x8, A[s * 2 + 1]);
      #pragma unroll
      for (int nf = 0; nf < NF; ++nf) {
        bf16x8 b;
        if constexpr (BCH > 0) b = *(const bf16x8*)&BsL[(((c0 + s) * NF + nf) * 64 + l) * 8];
        else                   b = __builtin_bit_cast(bf16x8, B[s * NF + nf]);
        acc[0][nf] = __builtin_amdgcn_mfma_f32_32x32x16_bf16(a0, b, acc[0][nf], 0, 0, 0);
        acc[1][nf] = __builtin_amdgcn_mfma_f32_32x32x16_bf16(a1, b, acc[1][nf], 0, 0, 0);
      }
    }
  };

  // 3-deep pipeline, statically-named banks (rotation verified iters=7/14/16/27/54)
  uint4 A0[4], A1[4], A2[4], B0[NB], B1[NB], B2[NB];
  LD(0, A0, B0);
  if (iters > 1) LD(1, A1, B1);
  for (int it = 0; it < iters; it += 3) {
    if (it + 2 < iters) LD(it + 2, A2, B2);
    MM(it, A0, B0);
    if (it + 3 < iters) LD(it + 3, A0, B0);
    if (it + 1 < iters) MM(it + 1, A1, B1);
    if (it + 4 < iters) LD(it + 4, A1, B1);
    if (it + 2 < iters) MM(it + 2, A2, B2);
  }

  const int fp32out = out_ext && !fbf;
  #pragma unroll
  for (int mm = 0; mm < 2; ++mm) {
    #pragma unroll
    for (int nf = 0; nf < NF; ++nf) {
      const int co = nf * 32 + lm;
      if (co >= Cout) continue;
      const float bv = (bias2 && co >= b2off) ? bf2f(bias2[co - b2off]) : bf2f(bias[co]);
      #pragma unroll
      for (int r = 0; r < 16; ++r) {
        const int m = (r & 3) + 8 * (r >> 2) + 4 * lh;
        const int p = M0 + (2 * w + mm) * 32 + m;
        if (p >= Nout) continue;
        float v = acc[mm][nf][r] + bv;
        if (out2 && co >= o2off) {
          if (v < 0.f) v = 0.f;                       // split path: always relu
          out2[(size_t)p * o2st + (co - o2off)] = f2bf(v);
        } else {
          if (resid) v += bf2f(resid[(size_t)p * ostride + coloff + co]);
          if (relu && v < 0.f) v = 0.f;
          const size_t ofs = (size_t)p * ostride + coloff + co;
          if (fp32out) ((float*)out)[ofs] = v;
          else         ((u16*)out)[ofs] = f2bf(v);
        }
      }
    }
  }
}

// ---------------------------------------------------------------------------
// Weight prep. mode 0: gemm fragments BTf[((chunk*NF+nf)*64+lane)*8+e] =
// W'[kk][co], co=nf*32+(lane&31), kk=chunk*16+(lane>>5)*8+e, W'=src[kk][Cout].
// mode 1: flat copy-convert. mode 3: fused block-diagonal (g01 ++ g11):
//   Cin=16 (ci<8 = h-half, ci>=8 = t-half), Cout=24 (co<16 from src=rw01,
//   co>=16 from src2=rw11); cross terms exact zero -> bit-exact fusion.
// ---------------------------------------------------------------------------
struct PrepJob {
  const void* src; const void* src2; long long eoff, eoff2; u16* dst;
  int nK, Cin, Cout, COPAD, KKpad, mode, count;
};
struct PrepArgs { PrepJob j[19]; };

__global__ void prep_k(PrepArgs a, const int* __restrict__ flags){
  PrepJob jb = a.j[blockIdx.y];
  const int fbf = flags[0];
  if (jb.mode == 1) {
    for (int t = blockIdx.x * 256 + threadIdx.x; t < jb.count; t += gridDim.x * 256)
      jb.dst[t] = cvt(jb.src, jb.eoff + t, fbf);
    return;
  }
  const int total = jb.COPAD * jb.KKpad;
  const int kkmax = jb.nK * jb.Cin;
  if (jb.mode == 3) {
    for (int t = blockIdx.x * 256 + threadIdx.x; t < total; t += gridDim.x * 256) {
      const int e  = t & 7;
      const int lj = (t >> 3) & 63;
      const int chunk = t >> 9;                 // NF=1
      const int co = lj & 31;
      const int kk = chunk * 16 + ((lj >> 5) << 3) + e;
      const int k = kk >> 4, ci = kk & 15;
      u16 v = 0;
      if (kk < kkmax && co < jb.Cout) {
        if (ci < 8 && co < 16)
          v = cvt(jb.src,  jb.eoff  + (long long)(k * 8 + ci) * 16 + co, fbf);
        else if (ci >= 8 && co >= 16)
          v = cvt(jb.src2, jb.eoff2 + (long long)(k * 8 + (ci - 8)) * 8 + (co - 16), fbf);
      }
      jb.dst[t] = v;
    }
    return;
  }
  const int NFj = jb.COPAD >> 5;            // 1 or 2
  for (int t = blockIdx.x * 256 + threadIdx.x; t < total; t += gridDim.x * 256) {
    const int e  = t & 7;
    const int lj = (t >> 3) & 63;
    const int cn = t >> 9;                  // chunk*NF + nf
    const int nf = cn & (NFj - 1);
    const int chunk = cn >> (NFj - 1);
    const int co = nf * 32 + (lj & 31);
    const int kk = chunk * 16 + ((lj >> 5) << 3) + e;
    u16 v = 0;
    if (co < jb.Cout && kk < kkmax)
      v = cvt(jb.src, jb.eoff + (long long)kk * jb.Cout + co, fbf);
    jb.dst[t] = v;
  }
}

// xsum = x_feat + f1_ref -> bf16, plus zero row at index N. 8 elems/thread.
__global__ void xsum_k(const void* __restrict__ xa, const void* __restrict__ xb,
                       u16* __restrict__ dst, int n8valid, int n8tot,
                       const int* __restrict__ flags){
  int t = blockIdx.x * 256 + threadIdx.x;
  if (t >= n8tot) return;
  const int fbf = flags[0];
  union { uint4 v; u16 h[8]; } O;
  if (t < n8valid) {
    if (fbf) {
      union { uint4 v; u16 h[8]; } A, B;
      A.v = ((const uint4*)xa)[t];
      B.v = ((const uint4*)xb)[t];
      #pragma unroll
      for (int e = 0; e < 8; ++e) O.h[e] = f2bf(bf2f(A.h[e]) + bf2f(B.h[e]));
    } else {
      const float4* fa = (const float4*)xa;
      const float4* fb = (const float4*)xb;
      float4 a0 = fa[2 * t], a1 = fa[2 * t + 1];
      float4 b0 = fb[2 * t], b1 = fb[2 * t + 1];
      O.h[0] = f2bf(a0.x + b0.x); O.h[1] = f2bf(a0.y + b0.y);
      O.h[2] = f2bf(a0.z + b0.z); O.h[3] = f2bf(a0.w + b0.w);
      O.h[4] = f2bf(a1.x + b1.x); O.h[5] = f2bf(a1.y + b1.y);
      O.h[6] = f2bf(a1.z + b1.z); O.h[7] = f2bf(a1.w + b1.w);
    }
  } else {
    O.v = make_uint4(0, 0, 0, 0);
  }
  ((uint4*)dst)[t] = O.v;
}

// zero the gather "no neighbor" rows (ws re-poisoned every call)
__global__ void zrows_k(u16* out1, int N, u16* od0, u16* od1, u16* ht, int N2){
  int t = threadIdx.x;
  if (t < 64) out1[(size_t)N * 64 + t] = 0;
  if (t < 32) od0[(size_t)N2 * 32 + t] = 0;
  if (t < 32) od1[(size_t)N2 * 32 + t] = 0;
  if (t < 16) ht[(size_t)N2 * 16 + t] = 0;
}

// ht[:,8:16] = relu(od @ W(32x8) + b)   one point/thread. W,b bf16 from ws.
__global__ void t8lin_k(const u16* __restrict__ od, const u16* __restrict__ wsrc,
                        const u16* __restrict__ bsrc, u16* __restrict__ ht, int N2){
  __shared__ u16 wl[256];
  int t = threadIdx.x;
  wl[t] = wsrc[t];
  __syncthreads();
  int p = blockIdx.x * 256 + t;
  if (p >= N2) return;
  union { uint4 v[4]; u16 h[32]; } R;
  const uint4* rp = (const uint4*)(od + (size_t)p * 32);
  R.v[0] = rp[0]; R.v[1] = rp[1]; R.v[2] = rp[2]; R.v[3] = rp[3];
  float acc[8];
  #pragma unroll
  for (int o = 0; o < 8; ++o) acc[o] = bf2f(bsrc[o]);
  #pragma unroll
  for (int c = 0; c < 32; ++c) {
    float f = bf2f(R.h[c]);
    #pragma unroll
    for (int o = 0; o < 8; ++o) acc[o] += f * bf2f(wl[c * 8 + o]);
  }
  union { uint4 v; u16 h[8]; } O;
  #pragma unroll
  for (int o = 0; o < 8; ++o) { float v = acc[o]; if (v < 0.f) v = 0.f; O.h[o] = f2bf(v); }
  *(uint4*)(ht + (size_t)p * 16 + 8) = O.v;
}

// odout[:,16:32] = t2 @ W(8x16) + b + odin[:,16:32]. W,b bf16 from ws.
__global__ void o1lin_k(const u16* __restrict__ t2, const u16* __restrict__ wsrc,
                        const u16* __restrict__ bsrc, const u16* __restrict__ odin,
                        u16* __restrict__ odout, int N2){
  __shared__ u16 wl[128];
  int t = threadIdx.x;
  if (t < 128) wl[t] = wsrc[t];
  __syncthreads();
  int p = blockIdx.x * 256 + t;
  if (p >= N2) return;
  union { uint4 v; u16 h[8]; } R; R.v = ((const uint4*)(t2 + (size_t)p * 8))[0];
  union { uint4 v[2]; u16 h[16]; } Rs;
  const uint4* rp = (const uint4*)(odin + (size_t)p * 32 + 16);
  Rs.v[0] = rp[0]; Rs.v[1] = rp[1];
  float acc[16];
  #pragma unroll
  for (int o = 0; o < 16; ++o) acc[o] = bf2f(bsrc[o]) + bf2f(Rs.h[o]);
  #pragma unroll
  for (int c = 0; c < 8; ++c) {
    float f = bf2f(R.h[c]);
    #pragma unroll
    for (int o = 0; o < 16; ++o) acc[o] += f * bf2f(wl[c * 16 + o]);
  }
  union { uint4 v[2]; u16 h[16]; } O;
  #pragma unroll
  for (int o = 0; o < 16; ++o) O.h[o] = f2bf(acc[o]);
  uint4* op = (uint4*)(odout + (size_t)p * 32 + 16);
  op[0] = O.v[0]; op[1] = O.v[1];
}

extern "C" void kernel_launch(void* const* d_in, const int* in_sizes, int n_in,
                              void* d_out, int out_size, void* d_ws, size_t ws_size,
                              hipStream_t stream) {
  const void* x_feat = d_in[0];
  const void* f1_ref = d_in[1];
  const void* w1   = d_in[2];
  const void* b1   = d_in[3];
  const void* wd   = d_in[4];
  const void* bd   = d_in[5];
  const void* rw00 = d_in[6];
  const void* rb00 = d_in[7];
  const void* rw01 = d_in[8];
  const void* rb01 = d_in[9];
  const void* rw10 = d_in[10];
  const void* rb10 = d_in[11];
  const void* rw11 = d_in[12];
  const void* rb11 = d_in[13];
  const void* rw12 = d_in[14];
  const void* rb12 = d_in[15];
  const void* w4   = d_in[16];
  const void* b4   = d_in[17];
  const void* idx1 = d_in[18];
  const void* idxd = d_in[19];
  const void* idx2 = d_in[20];

  const int N  = in_sizes[0] / 64;
  const int N2 = out_size / 8;

  const int nb1 = (N + 255) / 256;
  const int nb2 = (N2 + 255) / 256;
  const int Npad1 = nb1 * 256;
  const int Npad2 = nb2 * 256;

  // ---- workspace carve (256B aligned) ----
  size_t off = 0;
  auto carve = [&](size_t n) { void* p = (char*)d_ws + off; off = (off + n + 255) & ~(size_t)255; return p; };
  int* flags = (int*)carve(64 * sizeof(int));
  u16* xsum = (u16*)carve((size_t)(N + 1) * 64 * 2);
  u16* out1 = (u16*)carve((size_t)(N + 1) * 64 * 2);
  u16* od0  = (u16*)carve((size_t)(N2 + 1) * 32 * 2);
  u16* od1  = (u16*)carve((size_t)(N2 + 1) * 32 * 2);
  u16* ht   = (u16*)carve((size_t)(N2 + 1) * 16 * 2);   // h(0:8) ++ t8(8:16)
  u16* t2   = (u16*)carve((size_t)(N2 + 1) * 8 * 2);
  u16* smallw = (u16*)carve((size_t)2048 * 2);
  u16* BT1  = (u16*)carve((size_t)64 * 1728 * 2);
  u16* BTd  = (u16*)carve((size_t)32 * 512 * 2);
  u16* BT00 = (u16*)carve((size_t)3 * 32 * 864 * 2);
  u16* BTf1 = (u16*)carve((size_t)3 * 32 * 448 * 2);    // fused g01+g11
  u16* BT4  = (u16*)carve((size_t)32 * 864 * 2);
  const size_t base_off = off;
  // transposed idx maps (optional — legacy path if ws too small)
  int* idx1T = (int*)carve((size_t)27 * Npad1 * 4);
  int* idxdT = (int*)carve((size_t)8  * Npad2 * 4);
  int* idx2T = (int*)carve((size_t)28 * Npad2 * 4);   // k=27 pad plane
  const int useT = (off <= ws_size);
  if (base_off > ws_size) return;
  if (!useT) { idx1T = nullptr; idxdT = nullptr; idx2T = nullptr; }

  // smallw layout (bf16 elements)
  u16* cb1   = smallw + 0;     // 64
  u16* cbd   = smallw + 64;    // 32
  u16* crb00 = smallw + 96;    // 24
  u16* crb01 = smallw + 120;   // 48
  u16* crb10 = smallw + 168;   // 24
  u16* crb11 = smallw + 192;   // 24
  u16* crb12 = smallw + 216;   // 48
  u16* cb4   = smallw + 264;   // 8
  u16* crw10 = smallw + 272;   // 768
  u16* crw12 = smallw + 1040;  // 384

  detect_k<<<1, 256, 0, stream>>>((const u32*)x_feat, (const u32*)idx1, flags);

  // ---- weight prep ----
  PrepArgs pa;
  pa.j[0]  = { w1, nullptr, 0, 0, BT1, 27, 64, 64, 64, 1728, 0, 0 };
  pa.j[1]  = { wd, nullptr, 0, 0, BTd,  8, 64, 32, 32,  512, 0, 0 };
  for (int i = 0; i < 3; ++i) {
    pa.j[2 + i] = { rw00, nullptr, (long long)i * 6912, 0,
                    BT00 + (size_t)i * 32 * 864, 27, 32, 8, 32, 864, 0, 0 };
    pa.j[5 + i] = { rw01, rw11, (long long)i * 3456, (long long)i * 1728,
                    BTf1 + (size_t)i * 32 * 448, 27, 16, 24, 32, 448, 3, 0 };
  }
  pa.j[8]  = { w4, nullptr, 0, 0, BT4, 27, 32, 8, 32, 864, 0, 0 };
  pa.j[9]  = { b1,   nullptr, 0, 0, cb1,   0,0,0,0,0, 1, 64 };
  pa.j[10] = { bd,   nullptr, 0, 0, cbd,   0,0,0,0,0, 1, 32 };
  pa.j[11] = { rb00, nullptr, 0, 0, crb00, 0,0,0,0,0, 1, 24 };
  pa.j[12] = { rb01, nullptr, 0, 0, crb01, 0,0,0,0,0, 1, 48 };
  pa.j[13] = { rb10, nullptr, 0, 0, crb10, 0,0,0,0,0, 1, 24 };
  pa.j[14] = { rb11, nullptr, 0, 0, crb11, 0,0,0,0,0, 1, 24 };
  pa.j[15] = { rb12, nullptr, 0, 0, crb12, 0,0,0,0,0, 1, 48 };
  pa.j[16] = { b4,   nullptr, 0, 0, cb4,   0,0,0,0,0, 1, 8 };
  pa.j[17] = { rw10, nullptr, 0, 0, crw10, 0,0,0,0,0, 1, 768 };
  pa.j[18] = { rw12, nullptr, 0, 0, crw12, 0,0,0,0,0, 1, 384 };
  prep_k<<<dim3(432, 19), 256, 0, stream>>>(pa, flags);

  if (useT) {
    itr_k<<<nb1, 256, 0, stream>>>(idx1, 27, 27, N,  N,  Npad1, idx1T, flags);
    itr_k<<<nb2, 256, 0, stream>>>(idxd,  8,  8, N2, N,  Npad2, idxdT, flags);
    itr_k<<<nb2, 256, 0, stream>>>(idx2, 27, 28, N2, N2, Npad2, idx2T, flags);
  }

  const int n8valid = N * 8, n8tot = (N + 1) * 8;
  xsum_k<<<(n8tot + 255) / 256, 256, 0, stream>>>(x_feat, f1_ref, xsum, n8valid, n8tot, flags);
  zrows_k<<<1, 256, 0, stream>>>(out1, N, od0, od1, ht, N2);

  // conv1: 27x64->64, relu  (idx-LDS 27KB, B global)
  gconv<64, 2, 27, 0><<<nb1, 256, 0, stream>>>(xsum, N, idx1, 27, idx1T, Npad1, BT1, 54,
                                               cb1, nullptr, 0, nullptr,
                                               out1, 64, 0, 64, 1, nullptr, 0, 0,
                                               N, flags, 0);
  // down: 8x64->32, relu   (idx-LDS 8KB, B-LDS 32KB)
  gconv<64, 1, 8, 32><<<nb2, 256, 0, stream>>>(out1, N, idxd, 8, idxdT, Npad2, BTd, 16,
                                               cbd, nullptr, 0, nullptr,
                                               od0, 32, 0, 32, 1, nullptr, 0, 0,
                                               N2, flags, 0);
  // residual blocks
  for (int i = 0; i < 3; ++i) {
    u16* oin  = (i & 1) ? od1 : od0;
    u16* oout = (i & 1) ? od0 : od1;
    // g00: 27x32->8 relu -> ht[:,0:8]
    gconv<32, 1, 27, 0><<<nb2, 256, 0, stream>>>(oin, N2, idx2, 27, idx2T, Npad2,
                                                 BT00 + (size_t)i * 32 * 864, 27,
                                                 crb00 + i * 8, nullptr, 0, nullptr,
                                                 ht, 16, 0, 8, 1, nullptr, 0, 0,
                                                 N2, flags, 0);
    // t8 = relu(oin @ rw10 + rb10) -> ht[:,8:16]
    t8lin_k<<<nb2, 256, 0, stream>>>(oin, crw10 + i * 256, crb10 + i * 8, ht, N2);
    // fused g01+g11: 27x16->24; cols0-15 -> oout[:,0:16]+oin resid;
    // cols16-23 -> t2 (relu). Bit-exact vs separate kernels.
    gconv<16, 1, 28, 0><<<nb2, 256, 0, stream>>>(ht, N2, idx2, 27, idx2T, Npad2,
                                                 BTf1 + (size_t)i * 32 * 448, 14,
                                                 crb01 + i * 16, crb11 + i * 8, 16, oin,
                                                 oout, 32, 0, 24, 0, t2, 8, 16,
                                                 N2, flags, 0);
    o1lin_k<<<nb2, 256, 0, stream>>>(t2, crw12 + i * 128, crb12 + i * 16, oin, oout, N2);
  }
  // enc4: 27x32->8, no relu -> d_out (dtype per flags[0])
  gconv<32, 1, 27, 0><<<nb2, 256, 0, stream>>>(od1, N2, idx2, 27, idx2T, Npad2, BT4, 27,
                                               cb4, nullptr, 0, nullptr,
                                               d_out, 8, 0, 8, 0, nullptr, 0, 0,
                                               N2, flags, 1);
}

// Round 6
// 651.140 us; speedup vs baseline: 1.2923x; 1.0727x over previous
//
#include <hip/hip_runtime.h>
#include <cstdint>

typedef unsigned short u16;
typedef unsigned int   u32;

typedef __bf16 bf16_t;
typedef bf16_t bf16x8 __attribute__((ext_vector_type(8)));
typedef float  f32x16 __attribute__((ext_vector_type(16)));

__device__ __forceinline__ float bf2f(u16 v){ u32 u=((u32)v)<<16; float f; __builtin_memcpy(&f,&u,4); return f; }
__device__ __forceinline__ u16 f2bf(float f){ u32 u; __builtin_memcpy(&u,&f,4); u=(u+0x7FFFu+((u>>16)&1u))>>16; return (u16)u; }

// runtime-dtype element fetch -> bf16 bits. fbf=1: buffer is bf16; fbf=0: fp32.
__device__ __forceinline__ u16 cvt(const void* s, long long i, int fbf){
  return fbf ? ((const u16*)s)[i] : f2bf(((const float*)s)[i]);
}

// bijective chunked XCD swizzle (m204)
__device__ __forceinline__ int xcd_swz(int bo, int nwg){
  const int q = nwg >> 3, r = nwg & 7;
  const int xcd = bo & 7, lin = bo >> 3;
  return (xcd < r ? xcd * (q + 1) : r * (q + 1) + (xcd - r) * q) + lin;
}

// ---------------------------------------------------------------------------
// dtype detector (robust thresholds). flags[0]=bf16 inputs, flags[1]=int64 idx.
// ---------------------------------------------------------------------------
__global__ void detect_k(const u32* __restrict__ xf, const u32* __restrict__ ix,
                         int* __restrict__ flags){
  __shared__ int c0, c1;
  const int t = threadIdx.x;
  if (t == 0) { c0 = 0; c1 = 0; }
  __syncthreads();
  int a = 0, b = 0;
  for (int i = t; i < 1024; i += 256) {
    u32 w = xf[i];
    int e = (int)((w >> 7) & 0xFFu);
    if (e >= 100 && e <= 140) a++;
  }
  for (int i = t; i < 8192; i += 256) {
    u32 lo = ix[2 * i], hi = ix[2 * i + 1];
    if (lo != 0xFFFFFFFFu && hi != 0u && hi != 0xFFFFFFFFu) b++;
  }
  atomicAdd(&c0, a); atomicAdd(&c1, b);
  __syncthreads();
  if (t == 0) { flags[0] = (c0 >= 768) ? 1 : 0; flags[1] = (c1 == 0) ? 1 : 0; }
}

// ---------------------------------------------------------------------------
// idx transpose+clamp, coalesced both sides (LDS-tiled).
// idxT[k*Npad + p] = clamped int32 row (invalid/pad -> nsrc); planes
// k in [nK, nKpad) are all-nsrc.
// ---------------------------------------------------------------------------
__global__ __launch_bounds__(256) void itr_k(
    const void* __restrict__ idx, int nK, int nKpad, int Nout, int nsrc,
    int Npad, int* __restrict__ dst, const int* __restrict__ flags){
  __shared__ int tile[28][257];
  const int f64 = flags[1];
  const int t = threadIdx.x;
  const int p0 = blockIdx.x * 256;
  const int32_t*  __restrict__ i32 = (const int32_t*)idx;
  const long long* __restrict__ i64 = (const long long*)idx;
  int pl = t / nK;
  int k  = t - pl * nK;
  const int dp = 256 / nK, dk = 256 - dp * nK;
  while (pl < 256) {
    const int p = p0 + pl;
    int j = -1;
    if (p < Nout) {
      const size_t ii = (size_t)p * nK + k;
      j = f64 ? (int)i64[ii] : i32[ii];
    }
    tile[k][pl] = (j < 0 || j > nsrc) ? nsrc : j;
    pl += dp; k += dk;
    if (k >= nK) { k -= nK; pl += 1; }
  }
  __syncthreads();
  for (int kk = 0; kk < nKpad; ++kk) {
    const int v = (kk < nK) ? tile[kk][t] : nsrc;
    dst[(size_t)kk * Npad + p0 + t] = v;   // coalesced 4B writes
  }
}

// ---------------------------------------------------------------------------
// Gather-GEMM sparse conv, latency-tolerant.
//   out[p, coloff+co] = epi( sum_{k,ci} src[idx[p,k], ci] * W[k,ci,co] )
// - idx tile in LDS as PRE-SHIFTED BYTE OFFSETS (uint4-vectorized prologue).
// - B in LDS when BCH>0; else global (L2-hit).
// - 3-deep software pipeline, statically-named register banks.
// - split epilogue: cols >= o2off go to out2 (or, if L2, an LDS t2 tile)
//   with unconditional relu; bias2/b2off selects a second bias vector.
// - L2=1: in-kernel second stage (o1lin): out[:,16:32] = t2 @ l2w(8x16)
//   + l2b + resid[:,16:32], t2 from the LDS tile. Same fp32 order as the
//   standalone o1lin kernel.
// C/D: col=lane&31, row=(reg&3)+8*(reg>>2)+4*(lane>>5)  [m74/m101 verified]
// ---------------------------------------------------------------------------
template<int CIN, int NF, int NKP, int BCH, int L2>
__global__ __launch_bounds__(256) void gconv(
    const u16* __restrict__ src, int nsrc,           // zero row index = nsrc
    const void* __restrict__ idx, int nK,            // legacy path (idxT==null)
    const int* __restrict__ idxT, int Npad,          // transposed clamped idx
    const u16* __restrict__ BTf, int iters,          // iters = nchunk/2
    const u16* __restrict__ bias,
    const u16* __restrict__ bias2, int b2off,        // bias for co>=b2off (opt)
    const u16* __restrict__ resid,                   // may be null; stride=ostride
    void* __restrict__ out, int ostride, int coloff, int Cout,
    int relu,
    u16* __restrict__ out2, int o2st, int o2off,     // split output (opt, relu)
    const u16* __restrict__ l2w, const u16* __restrict__ l2b,  // L2 stage
    int Nout, const int* __restrict__ flags, int out_ext)
{
  constexpr int SH = (CIN == 64) ? 7 : (CIN == 32) ? 6 : (CIN == 16) ? 5 : 4;
  constexpr int NB = (BCH == 0) ? 2 * NF : 1;                // staged B regs
  __shared__ int idxL[NKP][256];
  __shared__ __align__(16) u16 BsL[(BCH > 0) ? BCH * NF * 512 : 8];
  __shared__ u16 t2L[L2 ? 256 : 1][8];
  __shared__ u16 l2wl[L2 ? 144 : 1];

  const int tid = threadIdx.x;
  const int w = tid >> 6, l = tid & 63;
  const int lm = l & 31, lh = l >> 5;
  const int kloc = lh * 8;
  const int M0 = xcd_swz(blockIdx.x, gridDim.x) * 256;
  const int fbf = flags[0], f64 = flags[1];
  const int pl0 = 2 * w * 32 + lm;      // in-block point slot, m-frag 0

  // ---- prologue: stage idx tile (byte offsets) + B tile, vectorized ----
  if (idxT) {
    for (int i = tid; i < NKP * 64; i += 256) {
      const int k = i >> 6, g = (i & 63) << 2;
      const uint4 v = *(const uint4*)(idxT + (size_t)k * Npad + M0 + g);
      *(int4*)&idxL[k][g] = make_int4((int)v.x << SH, (int)v.y << SH,
                                      (int)v.z << SH, (int)v.w << SH);
    }
  } else {
    for (int i = tid; i < NKP * 256; i += 256) {
      const int k = i >> 8, pl = i & 255, p = M0 + pl;
      int j = -1;
      if (k < nK && p < Nout) {
        const size_t ii = (size_t)p * nK + k;
        j = f64 ? (int)((const long long*)idx)[ii] : ((const int32_t*)idx)[ii];
      }
      const int r = (j < 0 || j > nsrc) ? nsrc : j;
      idxL[k][pl] = r << SH;
    }
  }
  if constexpr (BCH > 0) {
    for (int i = tid; i < BCH * NF * 64; i += 256)
      ((uint4*)BsL)[i] = ((const uint4*)BTf)[i];
  }
  if constexpr (L2) {
    if (tid < 144) l2wl[tid] = (tid < 128) ? l2w[tid] : l2b[tid - 128];
  }
  __syncthreads();

  f32x16 acc[2][NF];
  #pragma unroll
  for (int mm = 0; mm < 2; ++mm)
    #pragma unroll
    for (int nf = 0; nf < NF; ++nf)
      #pragma unroll
      for (int e = 0; e < 16; ++e) acc[mm][nf][e] = 0.f;

  // one stage = 2 chunks (one 16-wide K slice each)
  auto LD = [&](int it, uint4 (&A)[4], uint4 (&B)[NB]) {
    const int c0 = 2 * it;
    if constexpr (CIN >= 32) {
      const int k = (CIN == 64) ? (c0 >> 2) : (c0 >> 1);
      const int o0 = idxL[k][pl0];
      const int o1 = idxL[k][pl0 + 32];
      const char* s0 = (const char*)src + o0;
      const char* s1 = (const char*)src + o1;
      #pragma unroll
      for (int s = 0; s < 2; ++s) {
        const int c = c0 + s;
        const int ci2 = ((CIN == 64) ? (((c & 3) << 4) + kloc) : (((c & 1) << 4) + kloc)) * 2;
        A[s * 2 + 0] = *(const uint4*)(s0 + ci2);
        A[s * 2 + 1] = *(const uint4*)(s1 + ci2);
      }
    } else if constexpr (CIN == 16) {   // one tap per chunk, 32B rows
      #pragma unroll
      for (int s = 0; s < 2; ++s) {
        const int k = c0 + s;
        const int o0 = idxL[k][pl0];
        const int o1 = idxL[k][pl0 + 32];
        A[s * 2 + 0] = *(const uint4*)((const char*)src + o0 + lh * 16);
        A[s * 2 + 1] = *(const uint4*)((const char*)src + o1 + lh * 16);
      }
    } else {           // CIN == 8: k differs per chunk and lane-half
      #pragma unroll
      for (int s = 0; s < 2; ++s) {
        const int c = c0 + s;
        const int k = c * 2 + lh;
        const int o0 = idxL[k][pl0];
        const int o1 = idxL[k][pl0 + 32];
        A[s * 2 + 0] = *(const uint4*)((const char*)src + o0);
        A[s * 2 + 1] = *(const uint4*)((const char*)src + o1);
      }
    }
    if constexpr (BCH == 0) {
      #pragma unroll
      for (int s = 0; s < 2; ++s)
        #pragma unroll
        for (int nf = 0; nf < NF; ++nf)
          B[s * NF + nf] = *(const uint4*)(BTf + (((size_t)(c0 + s) * NF + nf) * 64 + l) * 8);
    }
  };

  auto MM = [&](int it, const uint4 (&A)[4], const uint4 (&B)[NB]) {
    const int c0 = 2 * it;
    __builtin_amdgcn_s_setprio(1);
    #pragma unroll
    for (int s = 0; s < 2; ++s) {
      const bf16x8 a0 = __builtin_bit_cast(bf16x8, A[s * 2 + 0]);
      const bf16x8 a1 = __builtin_bit_cast(bf16x8, A[s * 2 + 1]);
      #pragma unroll
      for (int nf = 0; nf < NF; ++nf) {
        bf16x8 b;
        if constexpr (BCH > 0) b = *(const bf16x8*)&BsL[(((c0 + s) * NF + nf) * 64 + l) * 8];
        else                   b = __builtin_bit_cast(bf16x8, B[s * NF + nf]);
        acc[0][nf] = __builtin_amdgcn_mfma_f32_32x32x16_bf16(a0, b, acc[0][nf], 0, 0, 0);
        acc[1][nf] = __builtin_amdgcn_mfma_f32_32x32x16_bf16(a1, b, acc[1][nf], 0, 0, 0);
      }
    }
    __builtin_amdgcn_s_setprio(0);
  };

  // 3-deep pipeline, statically-named banks (rotation verified iters=7/14/16/27/54)
  uint4 A0[4], A1[4], A2[4], B0[NB], B1[NB], B2[NB];
  LD(0, A0, B0);
  if (iters > 1) LD(1, A1, B1);
  for (int it = 0; it < iters; it += 3) {
    if (it + 2 < iters) LD(it + 2, A2, B2);
    MM(it, A0, B0);
    if (it + 3 < iters) LD(it + 3, A0, B0);
    if (it + 1 < iters) MM(it + 1, A1, B1);
    if (it + 4 < iters) LD(it + 4, A1, B1);
    if (it + 2 < iters) MM(it + 2, A2, B2);
  }

  const int fp32out = out_ext && !fbf;
  #pragma unroll
  for (int mm = 0; mm < 2; ++mm) {
    #pragma unroll
    for (int nf = 0; nf < NF; ++nf) {
      const int co = nf * 32 + lm;
      if (co >= Cout) continue;
      const float bv = (bias2 && co >= b2off) ? bf2f(bias2[co - b2off]) : bf2f(bias[co]);
      #pragma unroll
      for (int r = 0; r < 16; ++r) {
        const int m = (r & 3) + 8 * (r >> 2) + 4 * lh;
        const int pl = (2 * w + mm) * 32 + m;
        const int p = M0 + pl;
        if (p >= Nout) continue;
        float v = acc[mm][nf][r] + bv;
        if ((L2 || out2) && co >= o2off) {
          if (v < 0.f) v = 0.f;                       // split path: always relu
          if constexpr (L2) t2L[pl][co - o2off] = f2bf(v);
          else              out2[(size_t)p * o2st + (co - o2off)] = f2bf(v);
        } else {
          if (resid) v += bf2f(resid[(size_t)p * ostride + coloff + co]);
          if (relu && v < 0.f) v = 0.f;
          const size_t ofs = (size_t)p * ostride + coloff + co;
          if (fp32out) ((float*)out)[ofs] = v;
          else         ((u16*)out)[ofs] = f2bf(v);
        }
      }
    }
  }

  if constexpr (L2) {
    __syncthreads();
    const int p = M0 + tid;
    if (p < Nout) {
      union { uint4 v[2]; u16 h[16]; } Rs;
      const uint4* rp = (const uint4*)(resid + (size_t)p * 32 + 16);
      Rs.v[0] = rp[0]; Rs.v[1] = rp[1];
      float a[16];
      #pragma unroll
      for (int o = 0; o < 16; ++o) a[o] = bf2f(l2wl[128 + o]) + bf2f(Rs.h[o]);
      #pragma unroll
      for (int c = 0; c < 8; ++c) {
        const float f = bf2f(t2L[tid][c]);
        #pragma unroll
        for (int o = 0; o < 16; ++o) a[o] += f * bf2f(l2wl[c * 16 + o]);
      }
      union { uint4 v[2]; u16 h[16]; } O;
      #pragma unroll
      for (int o = 0; o < 16; ++o) O.h[o] = f2bf(a[o]);
      uint4* op = (uint4*)((u16*)out + (size_t)p * 32 + 16);
      op[0] = O.v[0]; op[1] = O.v[1];
    }
  }
}

// ---------------------------------------------------------------------------
// Weight prep. mode 0: gemm fragments BTf[((chunk*NF+nf)*64+lane)*8+e] =
// W'[kk][co], co=nf*32+(lane&31), kk=chunk*16+(lane>>5)*8+e, W'=src[kk][Cout].
// mode 1: flat copy-convert.
// mode 3: fused block-diagonal (g01 ++ g11): Cin=16 (ci<8 h-half / ci>=8
//   t-half), Cout=24 (co<16 rw01 / co>=16 rw11); cross terms exact zero.
// mode 4: g00 ++ center-tap 1x1 (rw10): Cin=32, Cout=16; co<8 = rw00[k][ci],
//   co 8-15 = (k==13 ? rw10[ci][co-8] : 0). 1x1 conv == center tap since
//   idx[p][13] = p always.
// ---------------------------------------------------------------------------
struct PrepJob {
  const void* src; const void* src2; long long eoff, eoff2; u16* dst;
  int nK, Cin, Cout, COPAD, KKpad, mode, count;
};
struct PrepArgs { PrepJob j[18]; };

__global__ void prep_k(PrepArgs a, const int* __restrict__ flags){
  PrepJob jb = a.j[blockIdx.y];
  const int fbf = flags[0];
  if (jb.mode == 1) {
    for (int t = blockIdx.x * 256 + threadIdx.x; t < jb.count; t += gridDim.x * 256)
      jb.dst[t] = cvt(jb.src, jb.eoff + t, fbf);
    return;
  }
  const int total = jb.COPAD * jb.KKpad;
  const int kkmax = jb.nK * jb.Cin;
  if (jb.mode == 3) {
    for (int t = blockIdx.x * 256 + threadIdx.x; t < total; t += gridDim.x * 256) {
      const int e  = t & 7;
      const int lj = (t >> 3) & 63;
      const int chunk = t >> 9;                 // NF=1
      const int co = lj & 31;
      const int kk = chunk * 16 + ((lj >> 5) << 3) + e;
      const int k = kk >> 4, ci = kk & 15;
      u16 v = 0;
      if (kk < kkmax && co < jb.Cout) {
        if (ci < 8 && co < 16)
          v = cvt(jb.src,  jb.eoff  + (long long)(k * 8 + ci) * 16 + co, fbf);
        else if (ci >= 8 && co >= 16)
          v = cvt(jb.src2, jb.eoff2 + (long long)(k * 8 + (ci - 8)) * 8 + (co - 16), fbf);
      }
      jb.dst[t] = v;
    }
    return;
  }
  if (jb.mode == 4) {
    for (int t = blockIdx.x * 256 + threadIdx.x; t < total; t += gridDim.x * 256) {
      const int e  = t & 7;
      const int lj = (t >> 3) & 63;
      const int chunk = t >> 9;                 // NF=1
      const int co = lj & 31;
      const int kk = chunk * 16 + ((lj >> 5) << 3) + e;
      const int k = kk >> 5, ci = kk & 31;
      u16 v = 0;
      if (kk < kkmax) {
        if (co < 8)
          v = cvt(jb.src, jb.eoff + (long long)(k * 32 + ci) * 8 + co, fbf);
        else if (co < 16 && k == 13)
          v = cvt(jb.src2, jb.eoff2 + (long long)ci * 8 + (co - 8), fbf);
      }
      jb.dst[t] = v;
    }
    return;
  }
  const int NFj = jb.COPAD >> 5;            // 1 or 2
  for (int t = blockIdx.x * 256 + threadIdx.x; t < total; t += gridDim.x * 256) {
    const int e  = t & 7;
    const int lj = (t >> 3) & 63;
    const int cn = t >> 9;                  // chunk*NF + nf
    const int nf = cn & (NFj - 1);
    const int chunk = cn >> (NFj - 1);
    const int co = nf * 32 + (lj & 31);
    const int kk = chunk * 16 + ((lj >> 5) << 3) + e;
    u16 v = 0;
    if (co < jb.Cout && kk < kkmax)
      v = cvt(jb.src, jb.eoff + (long long)kk * jb.Cout + co, fbf);
    jb.dst[t] = v;
  }
}

// xsum = x_feat + f1_ref -> bf16, plus zero row at index N. 8 elems/thread.
__global__ void xsum_k(const void* __restrict__ xa, const void* __restrict__ xb,
                       u16* __restrict__ dst, int n8valid, int n8tot,
                       const int* __restrict__ flags){
  int t = blockIdx.x * 256 + threadIdx.x;
  if (t >= n8tot) return;
  const int fbf = flags[0];
  union { uint4 v; u16 h[8]; } O;
  if (t < n8valid) {
    if (fbf) {
      union { uint4 v; u16 h[8]; } A, B;
      A.v = ((const uint4*)xa)[t];
      B.v = ((const uint4*)xb)[t];
      #pragma unroll
      for (int e = 0; e < 8; ++e) O.h[e] = f2bf(bf2f(A.h[e]) + bf2f(B.h[e]));
    } else {
      const float4* fa = (const float4*)xa;
      const float4* fb = (const float4*)xb;
      float4 a0 = fa[2 * t], a1 = fa[2 * t + 1];
      float4 b0 = fb[2 * t], b1 = fb[2 * t + 1];
      O.h[0] = f2bf(a0.x + b0.x); O.h[1] = f2bf(a0.y + b0.y);
      O.h[2] = f2bf(a0.z + b0.z); O.h[3] = f2bf(a0.w + b0.w);
      O.h[4] = f2bf(a1.x + b1.x); O.h[5] = f2bf(a1.y + b1.y);
      O.h[6] = f2bf(a1.z + b1.z); O.h[7] = f2bf(a1.w + b1.w);
    }
  } else {
    O.v = make_uint4(0, 0, 0, 0);
  }
  ((uint4*)dst)[t] = O.v;
}

// zero the gather "no neighbor" rows (ws re-poisoned every call)
__global__ void zrows_k(u16* out1, int N, u16* od0, u16* od1, u16* ht, int N2){
  int t = threadIdx.x;
  if (t < 64) out1[(size_t)N * 64 + t] = 0;
  if (t < 32) od0[(size_t)N2 * 32 + t] = 0;
  if (t < 32) od1[(size_t)N2 * 32 + t] = 0;
  if (t < 16) ht[(size_t)N2 * 16 + t] = 0;
}

extern "C" void kernel_launch(void* const* d_in, const int* in_sizes, int n_in,
                              void* d_out, int out_size, void* d_ws, size_t ws_size,
                              hipStream_t stream) {
  const void* x_feat = d_in[0];
  const void* f1_ref = d_in[1];
  const void* w1   = d_in[2];
  const void* b1   = d_in[3];
  const void* wd   = d_in[4];
  const void* bd   = d_in[5];
  const void* rw00 = d_in[6];
  const void* rb00 = d_in[7];
  const void* rw01 = d_in[8];
  const void* rb01 = d_in[9];
  const void* rw10 = d_in[10];
  const void* rb10 = d_in[11];
  const void* rw11 = d_in[12];
  const void* rb11 = d_in[13];
  const void* rw12 = d_in[14];
  const void* rb12 = d_in[15];
  const void* w4   = d_in[16];
  const void* b4   = d_in[17];
  const void* idx1 = d_in[18];
  const void* idxd = d_in[19];
  const void* idx2 = d_in[20];

  const int N  = in_sizes[0] / 64;
  const int N2 = out_size / 8;

  const int nb1 = (N + 255) / 256;
  const int nb2 = (N2 + 255) / 256;
  const int Npad1 = nb1 * 256;
  const int Npad2 = nb2 * 256;

  // ---- workspace carve (256B aligned) ----
  size_t off = 0;
  auto carve = [&](size_t n) { void* p = (char*)d_ws + off; off = (off + n + 255) & ~(size_t)255; return p; };
  int* flags = (int*)carve(64 * sizeof(int));
  u16* xsum = (u16*)carve((size_t)(N + 1) * 64 * 2);
  u16* out1 = (u16*)carve((size_t)(N + 1) * 64 * 2);
  u16* od0  = (u16*)carve((size_t)(N2 + 1) * 32 * 2);
  u16* od1  = (u16*)carve((size_t)(N2 + 1) * 32 * 2);
  u16* ht   = (u16*)carve((size_t)(N2 + 1) * 16 * 2);   // h(0:8) ++ t8(8:16)
  u16* smallw = (u16*)carve((size_t)2048 * 2);
  u16* BT1  = (u16*)carve((size_t)64 * 1728 * 2);
  u16* BTd  = (u16*)carve((size_t)32 * 512 * 2);
  u16* BT00 = (u16*)carve((size_t)3 * 32 * 864 * 2);    // fused g00+t8 (mode 4)
  u16* BTf1 = (u16*)carve((size_t)3 * 32 * 448 * 2);    // fused g01+g11 (mode 3)
  u16* BT4  = (u16*)carve((size_t)32 * 864 * 2);
  const size_t base_off = off;
  // transposed idx maps (optional — legacy path if ws too small)
  int* idx1T = (int*)carve((size_t)27 * Npad1 * 4);
  int* idxdT = (int*)carve((size_t)8  * Npad2 * 4);
  int* idx2T = (int*)carve((size_t)28 * Npad2 * 4);   // k=27 pad plane
  const int useT = (off <= ws_size);
  if (base_off > ws_size) return;
  if (!useT) { idx1T = nullptr; idxdT = nullptr; idx2T = nullptr; }

  // smallw layout (bf16 elements)
  u16* cb1   = smallw + 0;     // 64
  u16* cbd   = smallw + 64;    // 32
  u16* crb00 = smallw + 96;    // 24
  u16* crb01 = smallw + 120;   // 48
  u16* crb10 = smallw + 168;   // 24
  u16* crb11 = smallw + 192;   // 24
  u16* crb12 = smallw + 216;   // 48
  u16* cb4   = smallw + 264;   // 8
  u16* crw12 = smallw + 1040;  // 384

  detect_k<<<1, 256, 0, stream>>>((const u32*)x_feat, (const u32*)idx1, flags);

  // ---- weight prep ----
  PrepArgs pa;
  pa.j[0]  = { w1, nullptr, 0, 0, BT1, 27, 64, 64, 64, 1728, 0, 0 };
  pa.j[1]  = { wd, nullptr, 0, 0, BTd,  8, 64, 32, 32,  512, 0, 0 };
  for (int i = 0; i < 3; ++i) {
    pa.j[2 + i] = { rw00, rw10, (long long)i * 6912, (long long)i * 256,
                    BT00 + (size_t)i * 32 * 864, 27, 32, 16, 32, 864, 4, 0 };
    pa.j[5 + i] = { rw01, rw11, (long long)i * 3456, (long long)i * 1728,
                    BTf1 + (size_t)i * 32 * 448, 27, 16, 24, 32, 448, 3, 0 };
  }
  pa.j[8]  = { w4, nullptr, 0, 0, BT4, 27, 32, 8, 32, 864, 0, 0 };
  pa.j[9]  = { b1,   nullptr, 0, 0, cb1,   0,0,0,0,0, 1, 64 };
  pa.j[10] = { bd,   nullptr, 0, 0, cbd,   0,0,0,0,0, 1, 32 };
  pa.j[11] = { rb00, nullptr, 0, 0, crb00, 0,0,0,0,0, 1, 24 };
  pa.j[12] = { rb01, nullptr, 0, 0, crb01, 0,0,0,0,0, 1, 48 };
  pa.j[13] = { rb10, nullptr, 0, 0, crb10, 0,0,0,0,0, 1, 24 };
  pa.j[14] = { rb11, nullptr, 0, 0, crb11, 0,0,0,0,0, 1, 24 };
  pa.j[15] = { rb12, nullptr, 0, 0, crb12, 0,0,0,0,0, 1, 48 };
  pa.j[16] = { b4,   nullptr, 0, 0, cb4,   0,0,0,0,0, 1, 8 };
  pa.j[17] = { rw12, nullptr, 0, 0, crw12, 0,0,0,0,0, 1, 384 };
  prep_k<<<dim3(432, 18), 256, 0, stream>>>(pa, flags);

  if (useT) {
    itr_k<<<nb1, 256, 0, stream>>>(idx1, 27, 27, N,  N,  Npad1, idx1T, flags);
    itr_k<<<nb2, 256, 0, stream>>>(idxd,  8,  8, N2, N,  Npad2, idxdT, flags);
    itr_k<<<nb2, 256, 0, stream>>>(idx2, 27, 28, N2, N2, Npad2, idx2T, flags);
  }

  const int n8valid = N * 8, n8tot = (N + 1) * 8;
  xsum_k<<<(n8tot + 255) / 256, 256, 0, stream>>>(x_feat, f1_ref, xsum, n8valid, n8tot, flags);
  zrows_k<<<1, 256, 0, stream>>>(out1, N, od0, od1, ht, N2);

  // conv1: 27x64->64, relu  (idx-LDS 27KB, B global)
  gconv<64, 2, 27, 0, 0><<<nb1, 256, 0, stream>>>(xsum, N, idx1, 27, idx1T, Npad1, BT1, 54,
                                                  cb1, nullptr, 0, nullptr,
                                                  out1, 64, 0, 64, 1, nullptr, 0, 0,
                                                  nullptr, nullptr, N, flags, 0);
  // down: 8x64->32, relu   (idx-LDS 8KB, B-LDS 32KB)
  gconv<64, 1, 8, 32, 0><<<nb2, 256, 0, stream>>>(out1, N, idxd, 8, idxdT, Npad2, BTd, 16,
                                                  cbd, nullptr, 0, nullptr,
                                                  od0, 32, 0, 32, 1, nullptr, 0, 0,
                                                  nullptr, nullptr, N2, flags, 0);
  // residual blocks
  for (int i = 0; i < 3; ++i) {
    u16* oin  = (i & 1) ? od1 : od0;
    u16* oout = (i & 1) ? od0 : od1;
    // fused g00+t8: 27x32->16; cols0-7 (relu) -> ht[:,0:8];
    // cols8-15 = center-tap 1x1 (rw10,relu) -> ht[:,8:16]
    gconv<32, 1, 27, 0, 0><<<nb2, 256, 0, stream>>>(oin, N2, idx2, 27, idx2T, Npad2,
                                                    BT00 + (size_t)i * 32 * 864, 27,
                                                    crb00 + i * 8, crb10 + i * 8, 8, nullptr,
                                                    ht, 16, 0, 16, 1, ht + 8, 16, 8,
                                                    nullptr, nullptr, N2, flags, 0);
    // fused g01+g11+o1lin: 27x16->24; cols0-15 -> oout[:,0:16]+oin resid;
    // cols16-23 (t2, relu) -> LDS; then in-kernel: oout[:,16:32] =
    // t2 @ rw12 + rb12 + oin[:,16:32]. Bit-equivalent to the 3-kernel chain.
    gconv<16, 1, 28, 0, 1><<<nb2, 256, 0, stream>>>(ht, N2, idx2, 27, idx2T, Npad2,
                                                    BTf1 + (size_t)i * 32 * 448, 14,
                                                    crb01 + i * 16, crb11 + i * 8, 16, oin,
                                                    oout, 32, 0, 24, 0, nullptr, 0, 16,
                                                    crw12 + i * 128, crb12 + i * 16,
                                                    N2, flags, 0);
  }
  // enc4: 27x32->8, no relu -> d_out (dtype per flags[0])
  gconv<32, 1, 27, 0, 0><<<nb2, 256, 0, stream>>>(od1, N2, idx2, 27, idx2T, Npad2, BT4, 27,
                                                  cb4, nullptr, 0, nullptr,
                                                  d_out, 8, 0, 8, 0, nullptr, 0, 0,
                                                  nullptr, nullptr, N2, flags, 1);
}